// Round 1
// baseline (185.664 us; speedup 1.0000x reference)
//
#include <hip/hip_runtime.h>

#define TPB 1024
#define NBLK 512        // 2 blocks/CU x 256 CU = 32 waves/CU exactly
#define REPL 8          // 8-way pair replication
#define NENT 320        // indices 0..318 reachable (perm<=255 + yi/zi<=63), +1 inside pair -> 320

__device__ __forceinline__ float fade_f(float t) {
    // 6t^5 - 15t^4 + 10t^3 (Horner, fmaf)
    return t * t * t * fmaf(t, fmaf(t, 6.0f, -15.0f), 10.0f);
}

__device__ __forceinline__ float lerp_f(float a, float b, float t) {
    return fmaf(t, b - a, a);
}

// gi in [0,11] (clean leaf value, no masking needed).
// grad3 rows: 0..3 = (±1,±1,0), 4..7 = (±1,0,±1), 8..11 = (0,±1,±1)
// c1 = gi<8 ? dx : dy ; c2 = gi<4 ? dy : dz ; signs = gi&1, gi&2.
__device__ __forceinline__ float gdot_s(unsigned gi, float dx, float dy, float dz) {
    float c1 = (gi < 8u) ? dx : dy;
    float c2 = (gi < 4u) ? dy : dz;
    unsigned s1 = gi << 31;                   // bit0 -> sign of c1
    unsigned s2 = (gi << 30) & 0x80000000u;   // bit1 -> sign of c2
    return __uint_as_float(__float_as_uint(c1) ^ s1)
         + __uint_as_float(__float_as_uint(c2) ^ s2);
}

__global__ __launch_bounds__(TPB, 8) void perlin_kernel(
    const float* __restrict__ xg, const float* __restrict__ yg,
    const float* __restrict__ zg, const int* __restrict__ perm,
    float* __restrict__ out, int nquads)
{
    // Pair tables: entry i holds values for indices i and i+1 -> one ds_read_b64
    // replaces the old (idx, idx+64B) ds_read_b32 twins.
    //   Pa: addr table, value = perm[i&255] << 6  (pre-scaled to 64-B entry stride,
    //       CLEAN word -> next-level address is a single v_add, no mask)
    //   Pl: leaf table, value = perm[i&255] % 12  (gi only)
    // Mirroring to NENT=320 entries absorbs the %256 wrap (coords < 64).
    // Entry i copy c at element i*REPL + c -> entry stride 64 B, copy offset c*8 B.
    __shared__ uint2 Pa[NENT * REPL];   // 20 KB
    __shared__ uint2 Pl[NENT * REPL];   // 20 KB

    for (int s = threadIdx.x; s < NENT * REPL; s += TPB) {
        int i = s >> 3;  // REPL = 8
        unsigned p0 = (unsigned)perm[i & 255];
        unsigned p1 = (unsigned)perm[(i + 1) & 255];
        Pa[s] = make_uint2(p0 << 6, p1 << 6);
        Pl[s] = make_uint2(p0 % 12u, p1 % 12u);
    }
    __syncthreads();

    const char* Ta = (const char*)Pa + ((threadIdx.x & (REPL - 1)) << 3);
    const char* Tl = (const char*)Pl + ((threadIdx.x & (REPL - 1)) << 3);

    const float4* x4 = (const float4*)xg;
    const float4* y4 = (const float4*)yg;
    const float4* z4 = (const float4*)zg;
    float4* o4 = (float4*)out;

    const int stride = NBLK * TPB;
    for (int q = blockIdx.x * TPB + threadIdx.x; q < nquads; q += stride) {
        float4 xv = x4[q], yv = y4[q], zv = z4[q];
        float xa[4] = {xv.x, xv.y, xv.z, xv.w};
        float ya[4] = {yv.x, yv.y, yv.z, yv.w};
        float za[4] = {zv.x, zv.y, zv.z, zv.w};
        float4 res;
        float* rp = &res.x;

        #pragma unroll
        for (int e = 0; e < 4; ++e) {
            float X = xa[e], Y = ya[e], Z = za[e];
            // coords in [0,64): floor == trunc, indices in [0,63]
            int xi = (int)X, yi = (int)Y, zi = (int)Z;
            float xf = X - (float)xi, yf = Y - (float)yi, zf = Z - (float)zi;
            unsigned x6 = (unsigned)xi << 6;
            unsigned y6 = (unsigned)yi << 6;
            unsigned z6 = (unsigned)zi << 6;
            float u = fade_f(xf), v = fade_f(yf), w = fade_f(zf);
            float xf1 = xf - 1.0f, yf1 = yf - 1.0f, zf1 = zf - 1.0f;

            // hash tree: 1 + 2 + 4 ds_read_b64, addresses are pure adds
            uint2 AB  = *(const uint2*)(Ta + x6);        // (perm[xi]<<6, perm[xi+1]<<6)
            const char* Tay = Ta + y6;
            uint2 paa = *(const uint2*)(Tay + AB.x);     // (aa, ab) scaled
            uint2 pba = *(const uint2*)(Tay + AB.y);     // (ba, bb) scaled
            const char* Tlz = Tl + z6;
            uint2 qaa = *(const uint2*)(Tlz + paa.x);    // (gi_aaa, gi_aab)
            uint2 qab = *(const uint2*)(Tlz + paa.y);    // (gi_aba, gi_abb)
            uint2 qba = *(const uint2*)(Tlz + pba.x);    // (gi_baa, gi_bab)
            uint2 qbb = *(const uint2*)(Tlz + pba.y);    // (gi_bba, gi_bbb)

            float g_aaa = gdot_s(qaa.x, xf,  yf,  zf);
            float g_aab = gdot_s(qaa.y, xf,  yf,  zf1);
            float g_aba = gdot_s(qab.x, xf,  yf1, zf);
            float g_abb = gdot_s(qab.y, xf,  yf1, zf1);
            float g_baa = gdot_s(qba.x, xf1, yf,  zf);
            float g_bab = gdot_s(qba.y, xf1, yf,  zf1);
            float g_bba = gdot_s(qbb.x, xf1, yf1, zf);
            float g_bbb = gdot_s(qbb.y, xf1, yf1, zf1);

            float l1 = lerp_f(g_aaa, g_baa, u);
            float l2 = lerp_f(g_aba, g_bba, u);
            float l3 = lerp_f(g_aab, g_bab, u);
            float l4 = lerp_f(g_abb, g_bbb, u);
            float m1 = lerp_f(l1, l2, v);
            float m2 = lerp_f(l3, l4, v);
            rp[e] = lerp_f(m1, m2, w);
        }
        o4[q] = res;
    }
}

extern "C" void kernel_launch(void* const* d_in, const int* in_sizes, int n_in,
                              void* d_out, int out_size, void* d_ws, size_t ws_size,
                              hipStream_t stream) {
    const float* x   = (const float*)d_in[0];
    const float* y   = (const float*)d_in[1];
    const float* z   = (const float*)d_in[2];
    const int* perm  = (const int*)d_in[3];
    // d_in[4] (grad3) unused: gradients derived arithmetically from the index
    float* out = (float*)d_out;
    int nquads = out_size >> 2;  // 32*512*512 divisible by 4
    perlin_kernel<<<NBLK, TPB, 0, stream>>>(x, y, z, perm, out, nquads);
}

// Round 2
// 183.736 us; speedup vs baseline: 1.0105x; 1.0105x over previous
//
#include <hip/hip_runtime.h>

#define TPB 1024
#define NBLK 512        // 2 blocks/CU x 256 CU = 32 waves/CU exactly
#define REPL 8          // 8-way pair replication
#define NENT 320        // indices 0..318 reachable (perm<=255 + yi/zi<=63), +1 inside pair -> 320

__device__ __forceinline__ float fade_f(float t) {
    // 6t^5 - 15t^4 + 10t^3 (Horner, fmaf)
    return t * t * t * fmaf(t, fmaf(t, 6.0f, -15.0f), 10.0f);
}

__device__ __forceinline__ float lerp_f(float a, float b, float t) {
    return fmaf(t, b - a, a);
}

// gi in [0,11] (clean leaf value, no masking needed).
// grad3 rows: 0..3 = (±1,±1,0), 4..7 = (±1,0,±1), 8..11 = (0,±1,±1)
// c1 = gi<8 ? dx : dy ; c2 = gi<4 ? dy : dz ; signs = gi&1, gi&2.
__device__ __forceinline__ float gdot_s(unsigned gi, float dx, float dy, float dz) {
    float c1 = (gi < 8u) ? dx : dy;
    float c2 = (gi < 4u) ? dy : dz;
    unsigned s1 = gi << 31;                   // bit0 -> sign of c1
    unsigned s2 = (gi << 30) & 0x80000000u;   // bit1 -> sign of c2
    return __uint_as_float(__float_as_uint(c1) ^ s1)
         + __uint_as_float(__float_as_uint(c2) ^ s2);
}

// One fully-scalar Perlin evaluation. NO arrays, NO address-taken locals:
// everything must live in VGPRs (round-1 regression was these spilling to
// scratch: +128 MB write / +71 MB read traffic, dur 45->86 us).
__device__ __forceinline__ float perlin_e(float X, float Y, float Z,
                                          const char* Ta, const char* Tl) {
    // coords in [0,64): floor == trunc, indices in [0,63]
    int xi = (int)X, yi = (int)Y, zi = (int)Z;
    float xf = X - (float)xi, yf = Y - (float)yi, zf = Z - (float)zi;
    unsigned x6 = (unsigned)xi << 6;   // byte offsets, entry stride = 64 B
    unsigned y6 = (unsigned)yi << 6;
    unsigned z6 = (unsigned)zi << 6;
    float u = fade_f(xf), v = fade_f(yf), w = fade_f(zf);
    float xf1 = xf - 1.0f, yf1 = yf - 1.0f, zf1 = zf - 1.0f;

    // hash tree: 1 + 2 + 4 ds_read_b64, addresses are pure adds (clean words,
    // mirrored 320-entry table absorbs the %256 wrap)
    uint2 AB  = *(const uint2*)(Ta + x6);        // (perm[xi]<<6, perm[xi+1]<<6)
    const char* Tay = Ta + y6;
    uint2 paa = *(const uint2*)(Tay + AB.x);     // (aa, ab) scaled
    uint2 pba = *(const uint2*)(Tay + AB.y);     // (ba, bb) scaled
    const char* Tlz = Tl + z6;
    uint2 qaa = *(const uint2*)(Tlz + paa.x);    // (gi_aaa, gi_aab)
    uint2 qab = *(const uint2*)(Tlz + paa.y);    // (gi_aba, gi_abb)
    uint2 qba = *(const uint2*)(Tlz + pba.x);    // (gi_baa, gi_bab)
    uint2 qbb = *(const uint2*)(Tlz + pba.y);    // (gi_bba, gi_bbb)

    float g_aaa = gdot_s(qaa.x, xf,  yf,  zf);
    float g_aab = gdot_s(qaa.y, xf,  yf,  zf1);
    float g_aba = gdot_s(qab.x, xf,  yf1, zf);
    float g_abb = gdot_s(qab.y, xf,  yf1, zf1);
    float g_baa = gdot_s(qba.x, xf1, yf,  zf);
    float g_bab = gdot_s(qba.y, xf1, yf,  zf1);
    float g_bba = gdot_s(qbb.x, xf1, yf1, zf);
    float g_bbb = gdot_s(qbb.y, xf1, yf1, zf1);

    float l1 = lerp_f(g_aaa, g_baa, u);
    float l2 = lerp_f(g_aba, g_bba, u);
    float l3 = lerp_f(g_aab, g_bab, u);
    float l4 = lerp_f(g_abb, g_bbb, u);
    float m1 = lerp_f(l1, l2, v);
    float m2 = lerp_f(l3, l4, v);
    return lerp_f(m1, m2, w);
}

__global__ __launch_bounds__(TPB, 8) void perlin_kernel(
    const float* __restrict__ xg, const float* __restrict__ yg,
    const float* __restrict__ zg, const int* __restrict__ perm,
    float* __restrict__ out, int nquads)
{
    // Pair tables: entry i holds values for indices i and i+1 -> one ds_read_b64
    // replaces (idx, idx+1) b32 twins.
    //   Pa: addr table, value = perm[i&255] << 6 (pre-scaled, CLEAN -> add-only chain)
    //   Pl: leaf table, value = perm[i&255] % 12 (gi only)
    // Entry i copy c at element i*REPL + c -> entry stride 64 B, copy offset c*8 B.
    __shared__ uint2 Pa[NENT * REPL];   // 20 KB
    __shared__ uint2 Pl[NENT * REPL];   // 20 KB

    for (int s = threadIdx.x; s < NENT * REPL; s += TPB) {
        int i = s >> 3;  // REPL = 8
        unsigned p0 = (unsigned)perm[i & 255];
        unsigned p1 = (unsigned)perm[(i + 1) & 255];
        Pa[s] = make_uint2(p0 << 6, p1 << 6);
        Pl[s] = make_uint2(p0 % 12u, p1 % 12u);
    }
    __syncthreads();

    const char* Ta = (const char*)Pa + ((threadIdx.x & (REPL - 1)) << 3);
    const char* Tl = (const char*)Pl + ((threadIdx.x & (REPL - 1)) << 3);

    const float4* x4 = (const float4*)xg;
    const float4* y4 = (const float4*)yg;
    const float4* z4 = (const float4*)zg;
    float4* o4 = (float4*)out;

    const int stride = NBLK * TPB;
    for (int q = blockIdx.x * TPB + threadIdx.x; q < nquads; q += stride) {
        float4 xv = x4[q], yv = y4[q], zv = z4[q];
        float4 res;
        res.x = perlin_e(xv.x, yv.x, zv.x, Ta, Tl);
        res.y = perlin_e(xv.y, yv.y, zv.y, Ta, Tl);
        res.z = perlin_e(xv.z, yv.z, zv.z, Ta, Tl);
        res.w = perlin_e(xv.w, yv.w, zv.w, Ta, Tl);
        o4[q] = res;
    }
}

extern "C" void kernel_launch(void* const* d_in, const int* in_sizes, int n_in,
                              void* d_out, int out_size, void* d_ws, size_t ws_size,
                              hipStream_t stream) {
    const float* x   = (const float*)d_in[0];
    const float* y   = (const float*)d_in[1];
    const float* z   = (const float*)d_in[2];
    const int* perm  = (const int*)d_in[3];
    // d_in[4] (grad3) unused: gradients derived arithmetically from the index
    float* out = (float*)d_out;
    int nquads = out_size >> 2;  // 32*512*512 divisible by 4
    perlin_kernel<<<NBLK, TPB, 0, stream>>>(x, y, z, perm, out, nquads);
}

// Round 3
// 142.854 us; speedup vs baseline: 1.2997x; 1.2862x over previous
//
#include <hip/hip_runtime.h>

#define TPB 256
#define NBLOCKS 2048   // 8 blocks/CU x 256 CU: exactly fills 32 waves/CU (r0-proven config)
#define REPL 8         // 8-way PAIR replication -> 256 entries * 8 copies * 8 B = 16 KB (same as r0)

__device__ __forceinline__ float fade_f(float t) {
    // 6t^5 - 15t^4 + 10t^3 (Horner, fmaf)
    return t * t * t * fmaf(t, fmaf(t, 6.0f, -15.0f), 10.0f);
}

__device__ __forceinline__ float lerp_f(float a, float b, float t) {
    return fmaf(t, b - a, a);
}

// Packed leaf word w: bits 0..5 = gi = perm[...] % 12, bits 6..13 = perm value <<6.
// grad3 rows: 0..3 = (±1,±1,0), 4..7 = (±1,0,±1), 8..11 = (0,±1,±1)
// c1 = gi<8 ? dx : dy ; c2 = gi<4 ? dy : dz ; signs = gi&1, gi&2.
__device__ __forceinline__ float gdot_w(unsigned w, float dx, float dy, float dz) {
    unsigned gi = w & 0x3Fu;
    float c1 = (gi < 8u) ? dx : dy;
    float c2 = (gi < 4u) ? dy : dz;
    unsigned s1 = w << 31;                    // bit0 -> sign of c1
    unsigned s2 = (w << 30) & 0x80000000u;    // bit1 -> sign of c2
    return __uint_as_float(__float_as_uint(c1) ^ s1)
         + __uint_as_float(__float_as_uint(c2) ^ s2);
}

// One fully-scalar Perlin evaluation; no arrays, no address-taken locals.
// Tp already carries this thread's copy offset ((tid & 7) * 8 bytes).
// Entry byte stride = REPL*8 = 64 B, so idx<<6 IS the entry byte offset and
// (sum & 0x3FC0) wraps mod 256 entries while killing packed low-bit garbage
// (garbage < 64 and both clean terms are multiples of 64 -> no carry into bit 6).
__device__ __forceinline__ float perlin_e(float X, float Y, float Z, const char* Tp) {
    // coords in [0,64): floor == trunc, indices in [0,63]
    int xi = (int)X, yi = (int)Y, zi = (int)Z;
    float xf = X - (float)xi, yf = Y - (float)yi, zf = Z - (float)zi;
    unsigned x6 = (unsigned)xi << 6;   // <= 4032, in-bounds: no mask at level 1
    unsigned y6 = (unsigned)yi << 6;
    unsigned z6 = (unsigned)zi << 6;
    float u = fade_f(xf), v = fade_f(yf), w = fade_f(zf);
    float xf1 = xf - 1.0f, yf1 = yf - 1.0f, zf1 = zf - 1.0f;

    // hash tree: 1 + 2 + 4 ds_read_b64; each pair read yields entries (i, i+1)
    uint2 AB  = *(const uint2*)(Tp + x6);                  // (W[xi], W[xi+1])
    uint2 paa = *(const uint2*)(Tp + ((AB.x + y6) & 0x3FC0u)); // (aa, ab) packed
    uint2 pba = *(const uint2*)(Tp + ((AB.y + y6) & 0x3FC0u)); // (ba, bb) packed
    uint2 qaa = *(const uint2*)(Tp + ((paa.x + z6) & 0x3FC0u)); // (w_aaa, w_aab)
    uint2 qab = *(const uint2*)(Tp + ((paa.y + z6) & 0x3FC0u)); // (w_aba, w_abb)
    uint2 qba = *(const uint2*)(Tp + ((pba.x + z6) & 0x3FC0u)); // (w_baa, w_bab)
    uint2 qbb = *(const uint2*)(Tp + ((pba.y + z6) & 0x3FC0u)); // (w_bba, w_bbb)

    float g_aaa = gdot_w(qaa.x, xf,  yf,  zf);
    float g_aab = gdot_w(qaa.y, xf,  yf,  zf1);
    float g_aba = gdot_w(qab.x, xf,  yf1, zf);
    float g_abb = gdot_w(qab.y, xf,  yf1, zf1);
    float g_baa = gdot_w(qba.x, xf1, yf,  zf);
    float g_bab = gdot_w(qba.y, xf1, yf,  zf1);
    float g_bba = gdot_w(qbb.x, xf1, yf1, zf);
    float g_bbb = gdot_w(qbb.y, xf1, yf1, zf1);

    float l1 = lerp_f(g_aaa, g_baa, u);
    float l2 = lerp_f(g_aba, g_bba, u);
    float l3 = lerp_f(g_aab, g_bab, u);
    float l4 = lerp_f(g_abb, g_bbb, u);
    float m1 = lerp_f(l1, l2, v);
    float m2 = lerp_f(l3, l4, v);
    return lerp_f(m1, m2, w);
}

__global__ __launch_bounds__(TPB, 8) void perlin_kernel(
    const float* __restrict__ xg, const float* __restrict__ yg,
    const float* __restrict__ zg, const int* __restrict__ perm,
    float* __restrict__ out, int nquads)
{
    // Packed PAIR table, 16 KB (r0 footprint). Entry i, copy c at element i*REPL+c.
    // T[i*8+c] = ( W(perm[i]), W(perm[(i+1)&255]) ),  W(p) = (p<<6) | (p%12).
    // One ds_read_b64 replaces r0's (idx, idx+1) ds_read_b32 twins: 14 -> 7 LDS
    // instructions and one mask+add per PAIR instead of per lookup.
    __shared__ uint2 T[256 * REPL];

    for (int s = threadIdx.x; s < 256 * REPL; s += TPB) {
        int i = s >> 3;  // REPL = 8
        unsigned p0 = (unsigned)perm[i];
        unsigned p1 = (unsigned)perm[(i + 1) & 255];
        T[s] = make_uint2((p0 << 6) | (p0 % 12u), (p1 << 6) | (p1 % 12u));
    }
    __syncthreads();

    const char* Tp = (const char*)T + ((threadIdx.x & (REPL - 1)) << 3);

    const float4* x4 = (const float4*)xg;
    const float4* y4 = (const float4*)yg;
    const float4* z4 = (const float4*)zg;
    float4* o4 = (float4*)out;

    const int stride = gridDim.x * TPB;
    for (int q = blockIdx.x * TPB + threadIdx.x; q < nquads; q += stride) {
        float4 xv = x4[q], yv = y4[q], zv = z4[q];
        float4 res;
        res.x = perlin_e(xv.x, yv.x, zv.x, Tp);
        res.y = perlin_e(xv.y, yv.y, zv.y, Tp);
        res.z = perlin_e(xv.z, yv.z, zv.z, Tp);
        res.w = perlin_e(xv.w, yv.w, zv.w, Tp);
        o4[q] = res;
    }
}

extern "C" void kernel_launch(void* const* d_in, const int* in_sizes, int n_in,
                              void* d_out, int out_size, void* d_ws, size_t ws_size,
                              hipStream_t stream) {
    const float* x   = (const float*)d_in[0];
    const float* y   = (const float*)d_in[1];
    const float* z   = (const float*)d_in[2];
    const int* perm  = (const int*)d_in[3];
    // d_in[4] (grad3) unused: gradients derived arithmetically from the index
    float* out = (float*)d_out;
    int nquads = out_size >> 2;  // 32*512*512 divisible by 4
    perlin_kernel<<<NBLOCKS, TPB, 0, stream>>>(x, y, z, perm, out, nquads);
}

// Round 4
// 142.057 us; speedup vs baseline: 1.3070x; 1.0056x over previous
//
#include <hip/hip_runtime.h>

#define TPB 256
#define NBLOCKS 2048   // 8 blocks/CU x 256 CU: exactly fills 32 waves/CU (proven config)
#define REPL 8         // 8-way PAIR replication -> 256 entries * 8 copies * 8 B = 16 KB

__device__ __forceinline__ float fade_f(float t) {
    // 6t^5 - 15t^4 + 10t^3 (Horner, fmaf)
    return t * t * t * fmaf(t, fmaf(t, 6.0f, -15.0f), 10.0f);
}

__device__ __forceinline__ float lerp_f(float a, float b, float t) {
    return fmaf(t, b - a, a);
}

// Packed leaf word w: bits 0..5 = gi = perm[...] % 12, bits 6..13 = perm value <<6.
// grad3 rows: 0..3 = (±1,±1,0), 4..7 = (±1,0,±1), 8..11 = (0,±1,±1)
// c1 = gi<8 ? dx : dy ; c2 = gi<4 ? dy : dz ; signs = gi&1, gi&2.
__device__ __forceinline__ float gdot_w(unsigned w, float dx, float dy, float dz) {
    unsigned gi = w & 0x3Fu;
    float c1 = (gi < 8u) ? dx : dy;
    float c2 = (gi < 4u) ? dy : dz;
    unsigned s1 = w << 31;                    // bit0 -> sign of c1
    unsigned s2 = (w << 30) & 0x80000000u;    // bit1 -> sign of c2
    return __uint_as_float(__float_as_uint(c1) ^ s1)
         + __uint_as_float(__float_as_uint(c2) ^ s2);
}

// One fully-scalar Perlin evaluation; no arrays, no address-taken locals.
// Tp carries this thread's copy offset ((tid & 7) * 8 bytes).
// Entry byte stride = 64 B; (sum & 0x3FC0) wraps mod 256 entries and kills
// packed low-bit garbage (garbage < 64, clean terms are multiples of 64).
__device__ __forceinline__ float perlin_e(float X, float Y, float Z, const char* Tp) {
    // coords in [0,64): floor == trunc, indices in [0,63]
    int xi = (int)X, yi = (int)Y, zi = (int)Z;
    float xf = X - (float)xi, yf = Y - (float)yi, zf = Z - (float)zi;
    unsigned x6 = (unsigned)xi << 6;   // <= 4032, in-bounds: no mask at level 1
    unsigned y6 = (unsigned)yi << 6;
    unsigned z6 = (unsigned)zi << 6;
    float u = fade_f(xf), v = fade_f(yf), w = fade_f(zf);
    float xf1 = xf - 1.0f, yf1 = yf - 1.0f, zf1 = zf - 1.0f;

    // hash tree: 1 + 2 + 4 ds_read_b64; each pair read yields entries (i, i+1)
    uint2 AB  = *(const uint2*)(Tp + x6);                       // (W[xi], W[xi+1])
    uint2 paa = *(const uint2*)(Tp + ((AB.x + y6) & 0x3FC0u));  // (aa, ab)
    uint2 pba = *(const uint2*)(Tp + ((AB.y + y6) & 0x3FC0u));  // (ba, bb)
    uint2 qaa = *(const uint2*)(Tp + ((paa.x + z6) & 0x3FC0u)); // (w_aaa, w_aab)
    uint2 qab = *(const uint2*)(Tp + ((paa.y + z6) & 0x3FC0u)); // (w_aba, w_abb)
    uint2 qba = *(const uint2*)(Tp + ((pba.x + z6) & 0x3FC0u)); // (w_baa, w_bab)
    uint2 qbb = *(const uint2*)(Tp + ((pba.y + z6) & 0x3FC0u)); // (w_bba, w_bbb)

    float g_aaa = gdot_w(qaa.x, xf,  yf,  zf);
    float g_aab = gdot_w(qaa.y, xf,  yf,  zf1);
    float g_aba = gdot_w(qab.x, xf,  yf1, zf);
    float g_abb = gdot_w(qab.y, xf,  yf1, zf1);
    float g_baa = gdot_w(qba.x, xf1, yf,  zf);
    float g_bab = gdot_w(qba.y, xf1, yf,  zf1);
    float g_bba = gdot_w(qbb.x, xf1, yf1, zf);
    float g_bbb = gdot_w(qbb.y, xf1, yf1, zf1);

    float l1 = lerp_f(g_aaa, g_baa, u);
    float l2 = lerp_f(g_aba, g_bba, u);
    float l3 = lerp_f(g_aab, g_bab, u);
    float l4 = lerp_f(g_abb, g_bbb, u);
    float m1 = lerp_f(l1, l2, v);
    float m2 = lerp_f(l3, l4, v);
    return lerp_f(m1, m2, w);
}

__global__ __launch_bounds__(TPB, 8) void perlin_kernel(
    const float* __restrict__ xg, const float* __restrict__ yg,
    const float* __restrict__ zg, const int* __restrict__ perm,
    float* __restrict__ out, int nquads)
{
    // Packed PAIR table, 16 KB. T[i*8+c] = (W(perm[i]), W(perm[(i+1)&255])),
    // W(p) = (p<<6) | (p%12). One ds_read_b64 per (idx, idx+1) pair.
    __shared__ uint2 T[256 * REPL];

    for (int s = threadIdx.x; s < 256 * REPL; s += TPB) {
        int i = s >> 3;  // REPL = 8
        unsigned p0 = (unsigned)perm[i];
        unsigned p1 = (unsigned)perm[(i + 1) & 255];
        T[s] = make_uint2((p0 << 6) | (p0 % 12u), (p1 << 6) | (p1 % 12u));
    }
    __syncthreads();

    const char* Tp = (const char*)T + ((threadIdx.x & (REPL - 1)) << 3);

    const float4* x4 = (const float4*)xg;
    const float4* y4 = (const float4*)yg;
    const float4* z4 = (const float4*)zg;
    float4* o4 = (float4*)out;

    // ILP widening: 2 quads = 8 independent element chains per iteration.
    // r3 post-mortem: VALU 56%, LDS ~36%, nothing saturated -> latency-bound on
    // the 3-level dependent LDS chain with only 4 chains in flight. All 8
    // perlin_e calls sit in one basic block so the scheduler can overlap
    // quad-B VALU under quad-A LDS waits.
    const int stride = gridDim.x * TPB;   // 524288; nquads = 4*stride exactly
    for (int q = blockIdx.x * TPB + threadIdx.x; q < nquads; q += 2 * stride) {
        int q2 = q + stride;              // always < nquads (nquads == 4*stride)
        float4 xa = x4[q],  ya = y4[q],  za = z4[q];
        float4 xb = x4[q2], yb = y4[q2], zb = z4[q2];
        float4 ra, rb;
        ra.x = perlin_e(xa.x, ya.x, za.x, Tp);
        rb.x = perlin_e(xb.x, yb.x, zb.x, Tp);
        ra.y = perlin_e(xa.y, ya.y, za.y, Tp);
        rb.y = perlin_e(xb.y, yb.y, zb.y, Tp);
        ra.z = perlin_e(xa.z, ya.z, za.z, Tp);
        rb.z = perlin_e(xb.z, yb.z, zb.z, Tp);
        ra.w = perlin_e(xa.w, ya.w, za.w, Tp);
        rb.w = perlin_e(xb.w, yb.w, zb.w, Tp);
        o4[q]  = ra;
        o4[q2] = rb;
    }
}

extern "C" void kernel_launch(void* const* d_in, const int* in_sizes, int n_in,
                              void* d_out, int out_size, void* d_ws, size_t ws_size,
                              hipStream_t stream) {
    const float* x   = (const float*)d_in[0];
    const float* y   = (const float*)d_in[1];
    const float* z   = (const float*)d_in[2];
    const int* perm  = (const int*)d_in[3];
    // d_in[4] (grad3) unused: gradients derived arithmetically from the index
    float* out = (float*)d_out;
    int nquads = out_size >> 2;  // 32*512*512 divisible by 4
    perlin_kernel<<<NBLOCKS, TPB, 0, stream>>>(x, y, z, perm, out, nquads);
}